// Round 9
// baseline (1002.968 us; speedup 1.0000x reference)
//
#include <hip/hip_runtime.h>

// ---------------------------------------------------------------------------
// TransformerBlock (linear attention + FFN) on MI355X — bf16 MFMA GEMMs.
// R7: dw3gate float-LDS (cvt once), dw5 fused into attnmix, LN2 fused into
//     proj GEMM epilogue. 8 dispatches/group x 2 groups + 5 setup. ~169 MB ws.
// (Resubmitted unchanged after R8 GPU acquisition timeout.)
// ---------------------------------------------------------------------------

static constexpr int C   = 128;
static constexpr int L   = 16384;   // 128*128
static constexpr int BN  = 8;       // batch
static constexpr int GB  = 4;       // batches per launch group
static constexpr float SCALE = 0.35355339f;  // 1/sqrt(8)

typedef short bf16x8 __attribute__((ext_vector_type(8)));
typedef float f32x4  __attribute__((ext_vector_type(4)));

union ABFrag { bf16x8 v; uint4 q; };
union U4S8   { uint4 q; short s[8]; };
union U2S4   { uint2 q; short s[4]; };
union U1S2   { unsigned u; short s[2]; };

__device__ inline short f2bf(float f) {
  unsigned u = __float_as_uint(f);
  u += 0x7FFFu + ((u >> 16) & 1u);
  return (short)(u >> 16);
}
__device__ inline float bf2f(short s) {
  return __uint_as_float(((unsigned)(unsigned short)s) << 16);
}

// ------------------------- weight fp32 -> bf16 (K-pad) ---------------------
__global__ __launch_bounds__(256) void convert_w(const float* __restrict__ src,
                                                 short* __restrict__ dst,
                                                 int O, int K, int Kp) {
  int idx = blockIdx.x * 256 + threadIdx.x;
  if (idx >= O * Kp) return;
  int o = idx / Kp, k = idx - o * Kp;
  dst[idx] = (k < K) ? f2bf(src[o * K + k]) : (short)0;
}

// ------------------------------ MFMA GEMM ----------------------------------
// Y[o][l] = sum_k W[o][k] * XT[l][k]  (+bias) (+resid). No LDS.
// Block tile: 128 l x 64 o, 4 waves (2l x 2o), wave = 64l x 32o, BK=32.
template <int OUT_BF16, int HAS_BIAS, int HAS_RESID>
__global__ __launch_bounds__(256) void mfma_gemm(
    const short* __restrict__ XT, const short* __restrict__ Wb,
    void* __restrict__ Yv, const float* __restrict__ bias,
    const float* __restrict__ resid, int O, int Kp,
    size_t xbs, size_t ybs, size_t rbs) {
  const int z = blockIdx.z;
  XT += (size_t)z * xbs;
  if (HAS_RESID) resid += (size_t)z * rbs;
  const int lane = threadIdx.x & 63;
  const int wid  = threadIdx.x >> 6;
  const int wl = wid & 1, wo = wid >> 1;
  const int bl = blockIdx.x * 128;
  const int bo = blockIdx.y * 64;
  const int g   = lane >> 4;
  const int r15 = lane & 15;

  f32x4 acc[4][2];
#pragma unroll
  for (int m = 0; m < 4; ++m)
#pragma unroll
    for (int n = 0; n < 2; ++n) acc[m][n] = (f32x4){0.f, 0.f, 0.f, 0.f};

  const short* xrow[4];
#pragma unroll
  for (int m = 0; m < 4; ++m)
    xrow[m] = XT + (size_t)(bl + wl * 64 + m * 16 + r15) * Kp + g * 8;
  const short* wrow[2];
#pragma unroll
  for (int n = 0; n < 2; ++n)
    wrow[n] = Wb + (size_t)(bo + wo * 32 + n * 16 + r15) * Kp + g * 8;

  for (int k0 = 0; k0 < Kp; k0 += 32) {
    ABFrag a[4], b[2];
#pragma unroll
    for (int m = 0; m < 4; ++m) a[m].q = *(const uint4*)(xrow[m] + k0);
#pragma unroll
    for (int n = 0; n < 2; ++n) b[n].q = *(const uint4*)(wrow[n] + k0);
#pragma unroll
    for (int m = 0; m < 4; ++m)
#pragma unroll
      for (int n = 0; n < 2; ++n)
        acc[m][n] = __builtin_amdgcn_mfma_f32_16x16x32_bf16(a[m].v, b[n].v,
                                                            acc[m][n], 0, 0, 0);
  }

#pragma unroll
  for (int n = 0; n < 2; ++n) {
    int o = bo + wo * 32 + n * 16 + r15;
    if (o >= O) continue;
    float bv = HAS_BIAS ? bias[o] : 0.f;
#pragma unroll
    for (int m = 0; m < 4; ++m) {
      int l = bl + wl * 64 + m * 16 + (g << 2);
      f32x4 v = acc[m][n];
      if (HAS_BIAS) { v[0] += bv; v[1] += bv; v[2] += bv; v[3] += bv; }
      if (HAS_RESID) {
        const float4 r = *(const float4*)(resid + (size_t)o * L + l);
        v[0] += r.x; v[1] += r.y; v[2] += r.z; v[3] += r.w;
      }
      if (OUT_BF16) {
        uint2 s;
        s.x = (unsigned short)f2bf(v[0]) | ((unsigned)(unsigned short)f2bf(v[1]) << 16);
        s.y = (unsigned short)f2bf(v[2]) | ((unsigned)(unsigned short)f2bf(v[3]) << 16);
        *(uint2*)((short*)Yv + (size_t)z * ybs + (size_t)o * L + l) = s;
      } else {
        *(float4*)((float*)Yv + (size_t)z * ybs + (size_t)o * L + l) =
            make_float4(v[0], v[1], v[2], v[3]);
      }
    }
  }
}

// --------------- proj GEMM + bias + residual + LN2, fused ------------------
// Block: 64 pixels x ALL 128 output channels; 4 waves each own 32 o-chans.
// Emits x1 = proj+b+x (fp32, out) and xn2 = LN2(x1) (bf16 XT, yt2).
__global__ __launch_bounds__(256) void proj_ln_kernel(
    const short* __restrict__ XT, const short* __restrict__ Wb,
    const float* __restrict__ bias, const float* __restrict__ xres,
    const float* __restrict__ w2, const float* __restrict__ b2,
    float* __restrict__ out, short* __restrict__ yt2) {
  const int z = blockIdx.z;
  XT   += (size_t)z * L * C;
  xres += (size_t)z * C * L;
  out  += (size_t)z * C * L;
  yt2  += (size_t)z * L * C;
  const int lane = threadIdx.x & 63;
  const int wid  = threadIdx.x >> 6;   // o-chunk
  const int bl = blockIdx.x * 64;
  const int g = lane >> 4, r15 = lane & 15;

  __shared__ float lnb[128][68];       // [o][pixel], +4 pad
  __shared__ float red2[2][4][64];

  f32x4 acc[4][2];
#pragma unroll
  for (int m = 0; m < 4; ++m)
#pragma unroll
    for (int n = 0; n < 2; ++n) acc[m][n] = (f32x4){0.f, 0.f, 0.f, 0.f};

  const short* xrow[4];
#pragma unroll
  for (int m = 0; m < 4; ++m)
    xrow[m] = XT + (size_t)(bl + m * 16 + r15) * C + g * 8;
  const short* wrow[2];
#pragma unroll
  for (int n = 0; n < 2; ++n)
    wrow[n] = Wb + (size_t)(wid * 32 + n * 16 + r15) * C + g * 8;

  for (int k0 = 0; k0 < C; k0 += 32) {
    ABFrag a[4], b[2];
#pragma unroll
    for (int m = 0; m < 4; ++m) a[m].q = *(const uint4*)(xrow[m] + k0);
#pragma unroll
    for (int n = 0; n < 2; ++n) b[n].q = *(const uint4*)(wrow[n] + k0);
#pragma unroll
    for (int m = 0; m < 4; ++m)
#pragma unroll
      for (int n = 0; n < 2; ++n)
        acc[m][n] = __builtin_amdgcn_mfma_f32_16x16x32_bf16(a[m].v, b[n].v,
                                                            acc[m][n], 0, 0, 0);
  }

#pragma unroll
  for (int n = 0; n < 2; ++n) {
    int o = wid * 32 + n * 16 + r15;
    float bv = bias[o];
#pragma unroll
    for (int m = 0; m < 4; ++m) {
      int off = m * 16 + (g << 2);
      int l = bl + off;
      f32x4 v = acc[m][n];
      const float4 r = *(const float4*)(xres + (size_t)o * L + l);
      v[0] += bv + r.x; v[1] += bv + r.y; v[2] += bv + r.z; v[3] += bv + r.w;
      *(float4*)(out + (size_t)o * L + l) = make_float4(v[0], v[1], v[2], v[3]);
      *(float4*)&lnb[o][off] = make_float4(v[0], v[1], v[2], v[3]);
    }
  }
  __syncthreads();

  // LN over channels for 64 pixels; 4 threads/pixel
  const int px = threadIdx.x & 63, q = threadIdx.x >> 6;
  float vals[32];
  float s = 0.f, ss = 0.f;
#pragma unroll
  for (int j = 0; j < 32; ++j) {
    float v = lnb[q * 32 + j][px];
    vals[j] = v; s += v; ss += v * v;
  }
  red2[0][q][px] = s; red2[1][q][px] = ss;
  __syncthreads();
  float s4 = red2[0][0][px] + red2[0][1][px] + red2[0][2][px] + red2[0][3][px];
  float q4 = red2[1][0][px] + red2[1][1][px] + red2[1][2][px] + red2[1][3][px];
  float mu = s4 * (1.f / C);
  float var = q4 * (1.f / C) - mu * mu;
  float rstd = rsqrtf(var + 1e-5f);
  short* yr = yt2 + (size_t)(bl + px) * C + q * 32;
#pragma unroll
  for (int c0 = 0; c0 < 32; c0 += 8) {
    U4S8 u;
#pragma unroll
    for (int j = 0; j < 8; ++j)
      u.s[j] = f2bf((vals[c0 + j] - mu) * rstd * w2[q * 32 + c0 + j] + b2[q * 32 + c0 + j]);
    *(uint4*)(yr + c0) = u.q;
  }
}

// ------------------------------ LayerNorm (LN1) ----------------------------
__global__ __launch_bounds__(256) void ln_xt(const float* __restrict__ x,
                                             const float* __restrict__ w,
                                             const float* __restrict__ bias,
                                             short* __restrict__ yt) {
  const int z = blockIdx.z;
  x  += (size_t)z * C * L;
  yt += (size_t)z * L * C;
  const int lane = threadIdx.x & 63;
  const int wv   = threadIdx.x >> 6;
  const int l = blockIdx.x * 64 + lane;
  const float* xb = x + l;
  float vals[32];
  float s = 0.f, ss = 0.f;
#pragma unroll
  for (int j = 0; j < 32; ++j) {
    float v = xb[(size_t)(wv * 32 + j) * L];
    vals[j] = v; s += v; ss += v * v;
  }
  __shared__ float red[2][4][64];
  red[0][wv][lane] = s; red[1][wv][lane] = ss;
  __syncthreads();
  float s4 = red[0][0][lane] + red[0][1][lane] + red[0][2][lane] + red[0][3][lane];
  float q4 = red[1][0][lane] + red[1][1][lane] + red[1][2][lane] + red[1][3][lane];
  float mu = s4 * (1.f / C);
  float var = q4 * (1.f / C) - mu * mu;
  float rstd = rsqrtf(var + 1e-5f);
  short* yr = yt + (size_t)l * C + wv * 32;
#pragma unroll
  for (int c0 = 0; c0 < 32; c0 += 8) {
    U4S8 u;
#pragma unroll
    for (int j = 0; j < 8; ++j)
      u.s[j] = f2bf((vals[c0 + j] - mu) * rstd * w[wv * 32 + c0 + j] + bias[wv * 32 + c0 + j]);
    *(uint4*)(yr + c0) = u.q;
  }
}

__device__ inline void theta_shift8(const float* x, const float* sn,
                                    const float* cs, float* o) {
#pragma unroll
  for (int i = 0; i < 4; ++i) {
    float x0 = x[2 * i], x1 = x[2 * i + 1];
    o[2 * i]     = x0 * cs[2 * i]     - x1 * sn[2 * i];
    o[2 * i + 1] = x1 * cs[2 * i + 1] + x0 * sn[2 * i + 1];
  }
}

// rope table: sin/cos of i and i*1e-4 for i in [0,128)
#define ROPE_TABLE_DECL \
  __shared__ float ts0[128], ts4[128], tc0[128], tc4[128];
#define ROPE_TABLE_FILL(tid) \
  if ((tid) < 128) { \
    float s_, c_; \
    sincosf((float)(tid), &s_, &c_); ts0[tid] = s_; tc0[tid] = c_; \
    sincosf((float)(tid) * 1e-4f, &s_, &c_); ts4[tid] = s_; tc4[tid] = c_; \
  }
#define ROPE_LOOKUP(l, sn, cs) { \
    int h_ = (l) >> 7, w_ = (l) & 127; \
    sn[0] = sn[1] = ts0[h_]; sn[2] = sn[3] = ts4[h_]; \
    sn[4] = sn[5] = ts0[w_]; sn[6] = sn[7] = ts4[w_]; \
    cs[0] = cs[1] = tc0[h_]; cs[2] = cs[3] = tc4[h_]; \
    cs[4] = cs[5] = tc0[w_]; cs[6] = cs[7] = tc4[w_]; }

// ------------------- per-head kv / mean_k / mean_v sums --------------------
__global__ __launch_bounds__(256) void kvstats_kernel(const short* __restrict__ qkvo,
                                                      float* __restrict__ stats) {
  const int z = blockIdx.z;
  qkvo  += (size_t)z * 512 * L;
  stats += (size_t)z * 16 * 80;
  int n = blockIdx.y;
  int l0 = blockIdx.x * 1024;
  int tid = threadIdx.x;
  ROPE_TABLE_DECL
  ROPE_TABLE_FILL(tid)
  __syncthreads();
  const short* kb = qkvo + (size_t)(128 + n * 8) * L;
  const short* vb = qkvo + (size_t)(256 + n * 8) * L;
  float kv[8][8] = {};
  float mk[8] = {}, mv[8] = {};
  for (int l = l0 + tid; l < l0 + 1024; l += 256) {
    float sn[8], cs[8];
    ROPE_LOOKUP(l, sn, cs)
    float ke[8], kt[8], vv[8];
#pragma unroll
    for (int d = 0; d < 8; ++d) {
      float kval = bf2f(kb[(size_t)d * L + l]);
      ke[d] = kval > 0.f ? kval + 1.f : expf(kval);
      mk[d] += ke[d];
      vv[d] = bf2f(vb[(size_t)d * L + l]);
      mv[d] += vv[d];
    }
    theta_shift8(ke, sn, cs, kt);
#pragma unroll
    for (int d = 0; d < 8; ++d)
#pragma unroll
      for (int e = 0; e < 8; ++e) kv[d][e] = fmaf(kt[d], vv[e], kv[d][e]);
  }
  float valsr[80];
#pragma unroll
  for (int d = 0; d < 8; ++d)
#pragma unroll
    for (int e = 0; e < 8; ++e) valsr[d * 8 + e] = kv[d][e];
#pragma unroll
  for (int d = 0; d < 8; ++d) { valsr[64 + d] = mk[d]; valsr[72 + d] = mv[d]; }
#pragma unroll
  for (int i = 0; i < 80; ++i) {
    float v = valsr[i];
#pragma unroll
    for (int off = 32; off > 0; off >>= 1) v += __shfl_down(v, off);
    valsr[i] = v;
  }
  __shared__ float red[4][80];
  int lane = tid & 63, wid = tid >> 6;
  if (lane == 0) {
#pragma unroll
    for (int i = 0; i < 80; ++i) red[wid][i] = valsr[i];
  }
  __syncthreads();
  if (tid < 80) {
    float s2 = red[0][tid] + red[1][tid] + red[2][tid] + red[3][tid];
    atomicAdd(&stats[n * 80 + tid], s2);
  }
}

// ---- attn mix + fused lepe dwconv5x5: XT out = (res + lepe) * o_gate ------
// Block: 256 pixels (2 rows x 128 cols) for one head. v tile (6 rows) in LDS.
__global__ __launch_bounds__(256) void attnmix_kernel(const short* __restrict__ qkvo,
                                                      const float* __restrict__ stats,
                                                      const float* __restrict__ wdw,
                                                      const float* __restrict__ bdw,
                                                      short* __restrict__ outt) {
  const int z = blockIdx.z;
  qkvo  += (size_t)z * 512 * L;
  stats += (size_t)z * 16 * 80;
  outt  += (size_t)z * L * C;
  const int n = blockIdx.y;
  const int n8 = n * 8;
  const int tid = threadIdx.x;
  const int l0 = blockIdx.x * 256;
  const int y0 = l0 >> 7;             // 2 output rows y0, y0+1
  ROPE_TABLE_DECL
  __shared__ float kvs[64], mks[8], mvs[8];
  __shared__ float t5[8][6][128];     // v tile fp32, rows y0-2..y0+3
  __shared__ float wc[8][25];
  __shared__ float lb8[8];
  ROPE_TABLE_FILL(tid)
  else if (tid < 192)  kvs[tid - 128] = stats[n * 80 + tid - 128] * (SCALE / (float)L);
  else if (tid < 200)  mks[tid - 192] = stats[n * 80 + tid - 128] * (1.f / (float)L);
  else if (tid < 208)  mvs[tid - 200] = stats[n * 80 + tid - 128] * (1.f / (float)L);
  for (int idx = tid; idx < 200; idx += 256)
    wc[idx / 25][idx % 25] = wdw[(n8 + idx / 25) * 25 + idx % 25];
  if (tid < 8) lb8[tid] = bdw[n8 + tid];
  // stage v tile: 8 ch x 6 rows x 128 cols (bf16 -> fp32)
  for (int idx = tid; idx < 768; idx += 256) {
    int q = idx & 15, u = idx >> 4;
    int row = u % 6, e = u / 6;
    int gy = y0 - 2 + row;
    U4S8 v; v.q = make_uint4(0u, 0u, 0u, 0u);
    if (gy >= 0 && gy < 128)
      v.q = *(const uint4*)(qkvo + (size_t)(256 + n8 + e) * L + gy * 128 + q * 8);
    float4 lo = make_float4(bf2f(v.s[0]), bf2f(v.s[1]), bf2f(v.s[2]), bf2f(v.s[3]));
    float4 hi = make_float4(bf2f(v.s[4]), bf2f(v.s[5]), bf2f(v.s[6]), bf2f(v.s[7]));
    *(float4*)&t5[e][row][q * 8] = lo;
    *(float4*)&t5[e][row][q * 8 + 4] = hi;
  }
  __syncthreads();

  const int l = l0 + tid;
  const int rr = tid >> 7;            // 0/1 -> stage rows rr+2 center
  const int col = tid & 127;
  const short* qb = qkvo + (size_t)n8 * L + l;
  const short* ob = qkvo + (size_t)(384 + n8) * L + l;
  float qe[8];
#pragma unroll
  for (int d = 0; d < 8; ++d) {
    float qv = bf2f(qb[(size_t)d * L]);
    qe[d] = qv > 0.f ? qv + 1.f : expf(qv);
  }
  float z2 = 0.f;
#pragma unroll
  for (int d = 0; d < 8; ++d) z2 += qe[d] * mks[d];
  z2 *= SCALE;
  float sn[8], cs[8];
  ROPE_LOOKUP(l, sn, cs)
  float qt[8];
  theta_shift8(qe, sn, cs, qt);
  float coef = 1.f + 1.f / (z2 + 1e-6f);
  U4S8 u;
#pragma unroll
  for (int e = 0; e < 8; ++e) {
    float r = 0.f;
#pragma unroll
    for (int d = 0; d < 8; ++d) r = fmaf(qt[d], kvs[d * 8 + e], r);
    float res = r * coef - z2 * mvs[e];
    // lepe: 5x5 depthwise on v channel n8+e at (y0+rr, col)
    float lp = lb8[e];
#pragma unroll
    for (int i = 0; i < 5; ++i) {
      const float* row = &t5[e][rr + i][0];
#pragma unroll
      for (int j = 0; j < 5; ++j) {
        int cc = col - 2 + j;
        float vv = (cc >= 0 && cc < 128) ? row[cc] : 0.f;
        lp = fmaf(vv, wc[e][i * 5 + j], lp);
      }
    }
    u.s[e] = f2bf((res + lp) * bf2f(ob[(size_t)e * L]));
  }
  *(uint4*)(outt + (size_t)l * C + n8) = u.q;
}

// ---------------- FFN: depthwise 3x3 + GELU gate -> XT[l][352] -------------
// Stripe 8 rows x 128 cols; 2 output channels/block; float LDS (cvt once).
__global__ __launch_bounds__(256) void dw3gate_kernel(const short* __restrict__ p,
                                                      const float* __restrict__ wdw,
                                                      short* __restrict__ gxt) {
  const int z = blockIdx.z;
  p   += (size_t)z * 680 * L;
  gxt += (size_t)z * L * 352;
  const int ty0 = blockIdx.x * 8;      // 16 row tiles
  const int c0  = blockIdx.y * 2;      // 176 chunks (incl. pad 340..351)
  __shared__ float tile[4][10][128];   // slot = half*2+ch, fp32, 20KB
  __shared__ float wt[4][9];
  const int tid = threadIdx.x;
  if (tid < 36) {
    int slot = tid / 9, j = tid % 9;
    int half = slot >> 1, cc = c0 + (slot & 1);
    wt[slot][j] = (cc < 340) ? wdw[(half * 340 + cc) * 9 + j] : 0.f;
  }
  for (int idx = tid; idx < 640; idx += 256) {
    int q = idx & 15, u = idx >> 4;       // u: 0..39
    int row = u % 10, slot = u / 10;      // slot: 0..3
    int cc = c0 + (slot & 1), half = slot >> 1;
    int gy = ty0 + row - 1;
    U4S8 v; v.q = make_uint4(0u, 0u, 0u, 0u);
    if (cc < 340 && gy >= 0 && gy < 128)
      v.q = *(const uint4*)(p + (size_t)(half * 340 + cc) * L + gy * 128 + q * 8);
    float4 lo = make_float4(bf2f(v.s[0]), bf2f(v.s[1]), bf2f(v.s[2]), bf2f(v.s[3]));
    float4 hi = make_float4(bf2f(v.s[4]), bf2f(v.s[5]), bf2f(v.s[6]), bf2f(v.s[7]));
    *(float4*)&tile[slot][row][q * 8] = lo;
    *(float4*)&tile[slot][row][q * 8 + 4] = hi;
  }
  __syncthreads();
  const int r = tid >> 5, cg = (tid & 31) * 4;
  U1S2 ou[4];
#pragma unroll
  for (int ch = 0; ch < 2; ++ch) {
    float accA[4] = {0.f, 0.f, 0.f, 0.f};
    float accB[4] = {0.f, 0.f, 0.f, 0.f};
#pragma unroll
    for (int half = 0; half < 2; ++half) {
      float* acc = half ? accB : accA;
      const float* w9 = wt[half * 2 + ch];
#pragma unroll
      for (int i = 0; i < 3; ++i) {
        const float* row = &tile[half * 2 + ch][r + i][0];
        float v[6];
        v[0] = (cg - 1 >= 0) ? row[cg - 1] : 0.f;
        float4 m = *(const float4*)&row[cg];
        v[1] = m.x; v[2] = m.y; v[3] = m.z; v[4] = m.w;
        v[5] = (cg + 4 < 128) ? row[cg + 4] : 0.f;
#pragma unroll
        for (int cc = 0; cc < 4; ++cc)
#pragma unroll
          for (int j = 0; j < 3; ++j)
            acc[cc] = fmaf(v[cc + j], w9[i * 3 + j], acc[cc]);
      }
    }
#pragma unroll
    for (int cc = 0; cc < 4; ++cc) {
      float a = accA[cc];
      float ge = 0.5f * a * (1.f + erff(a * 0.70710678f));
      ou[cc].s[ch] = f2bf(ge * accB[cc]);
    }
  }
#pragma unroll
  for (int cc = 0; cc < 4; ++cc) {
    int pix = (ty0 + r) * 128 + cg + cc;
    *(unsigned*)(gxt + (size_t)pix * 352 + c0) = ou[cc].u;
  }
}

// ---------------------------------------------------------------------------
extern "C" void kernel_launch(void* const* d_in, const int* in_sizes, int n_in,
                              void* d_out, int out_size, void* d_ws, size_t ws_size,
                              hipStream_t stream) {
  const float* x        = (const float*)d_in[0];
  const float* ln1_w    = (const float*)d_in[1];
  const float* ln1_b    = (const float*)d_in[2];
  const float* qkvo_w   = (const float*)d_in[3];
  const float* qkvo_b   = (const float*)d_in[4];
  const float* lepe_w   = (const float*)d_in[5];
  const float* lepe_b   = (const float*)d_in[6];
  const float* proj_w   = (const float*)d_in[7];
  const float* proj_b   = (const float*)d_in[8];
  const float* ln2_w    = (const float*)d_in[9];
  const float* ln2_b    = (const float*)d_in[10];
  const float* ffn_in_w = (const float*)d_in[11];
  const float* ffn_dw_w = (const float*)d_in[12];
  const float* ffn_out_w= (const float*)d_in[13];
  float* out = (float*)d_out;

  // element strides per batch
  const size_t QKVO_S = (size_t)512 * L;
  const size_t P_S    = (size_t)680 * L;
  const size_t XN_S   = (size_t)L * 128;
  const size_t GXT_S  = (size_t)L * 352;
  const size_t XCL_S  = (size_t)C * L;

  // workspace layout (bytes)
  const size_t A_OFF    = 0;               // 89,128,960 = GB*680*L*2 (qkvo|p)
  const size_t XN_OFF   = 89128960ull;     // 16,777,216 (ln1 out / attn_in)
  const size_t XN2_OFF  = 105906176ull;    // 16,777,216 (xn2 from proj_ln)
  const size_t B_OFF    = 122683392ull;    // 46,137,344 (gxt)
  const size_t STAT_OFF = 168820736ull;    //     40,960
  const size_t WQ_OFF   = 168861696ull;    //    131,072
  const size_t WP_OFF   = 168992768ull;    //     32,768
  const size_t WFI_OFF  = 169025536ull;    //    174,080
  const size_t WFO_OFF  = 169199616ull;    //     90,112
  const size_t NEEDED   = 169289728ull;    // ~169.3 MB
  if (ws_size < NEEDED) return;

  char* ws = (char*)d_ws;
  short* qbuf  = (short*)(ws + A_OFF);
  short* pbuf  = (short*)(ws + A_OFF);
  short* xnbuf = (short*)(ws + XN_OFF);
  short* xn2   = (short*)(ws + XN2_OFF);
  short* gxt   = (short*)(ws + B_OFF);
  float* stats = (float*)(ws + STAT_OFF);
  short* wq    = (short*)(ws + WQ_OFF);
  short* wp    = (short*)(ws + WP_OFF);
  short* wfi   = (short*)(ws + WFI_OFF);
  short* wfo   = (short*)(ws + WFO_OFF);

  convert_w<<<dim3((512 * 128 + 255) / 256), 256, 0, stream>>>(qkvo_w, wq, 512, 128, 128);
  convert_w<<<dim3((128 * 128 + 255) / 256), 256, 0, stream>>>(proj_w, wp, 128, 128, 128);
  convert_w<<<dim3((680 * 128 + 255) / 256), 256, 0, stream>>>(ffn_in_w, wfi, 680, 128, 128);
  convert_w<<<dim3((128 * 352 + 255) / 256), 256, 0, stream>>>(ffn_out_w, wfo, 128, 340, 352);
  hipMemsetAsync(stats, 0, 128 * 80 * sizeof(float), stream);

  for (int gb = 0; gb < BN / GB; ++gb) {
    const float* xg   = x   + (size_t)gb * GB * XCL_S;
    float*       outg = out + (size_t)gb * GB * XCL_S;
    float*       st_g = stats + (size_t)gb * GB * 16 * 80;

    // K1: LN1 -> xn XT (bf16)
    ln_xt<<<dim3(256, 1, GB), 256, 0, stream>>>(xg, ln1_w, ln1_b, xnbuf);
    // K2: qkvo GEMM (O=512, K=128) -> qbuf bf16 [512][L]
    mfma_gemm<1, 1, 0><<<dim3(128, 8, GB), 256, 0, stream>>>(
        xnbuf, wq, qbuf, qkvo_b, nullptr, 512, 128, XN_S, QKVO_S, 0);
    // K3: per-head stats
    kvstats_kernel<<<dim3(16, 16, GB), 256, 0, stream>>>(qbuf, st_g);
    // K4: attention mix + fused lepe -> attn_in XT (reuse XN)
    attnmix_kernel<<<dim3(64, 16, GB), 256, 0, stream>>>(qbuf, st_g, lepe_w,
                                                         lepe_b, xnbuf);
    // K5: proj GEMM + bias + resid + LN2 -> out (x1 fp32) + xn2 XT
    proj_ln_kernel<<<dim3(256, 1, GB), 256, 0, stream>>>(
        xnbuf, wp, proj_b, xg, ln2_w, ln2_b, outg, xn2);
    // K6: ffn_in GEMM (O=680, K=128) -> p (bf16 [680][L], reuse A)
    mfma_gemm<1, 0, 0><<<dim3(128, 11, GB), 256, 0, stream>>>(
        xn2, wfi, pbuf, nullptr, nullptr, 680, 128, XN_S, P_S, 0);
    // K7: dwconv3x3 + GELU gate -> g XT [L][352]
    dw3gate_kernel<<<dim3(16, 176, GB), 256, 0, stream>>>(pbuf, ffn_dw_w, gxt);
    // K8: ffn_out GEMM (O=128, Kp=352) + residual x1 -> out (in place)
    mfma_gemm<0, 0, 1><<<dim3(128, 2, GB), 256, 0, stream>>>(
        gxt, wfo, outg, nullptr, outg, 128, 352, GXT_S, XCL_S, XCL_S);
  }
}